// Round 4
// baseline (1286.021 us; speedup 1.0000x reference)
//
#include <hip/hip_runtime.h>

typedef unsigned long long ull;
typedef float f32x4 __attribute__((ext_vector_type(4)));

#define BB 2
#define QQ 300
#define CC 80
#define KK 100
#define HM 200
#define WM 200

// ---------------------------------------------------------------------------
// Kernel A: per-batch top-100 via 3-round radix select (11/11/10 bits) on
// sigmoid keys (float bits; all positive -> uint order == float order).
// Round 0 computes keys from logits (expf, bit-identical ordering to JAX's
// f32 sigmoid) and caches them in ws; rounds 1-2 + collect re-read cached
// keys. 1024 threads (16 waves). Exact JAX tie-break (value desc, index
// asc). Also zeroes per-query accumulators + done counters, writes labels +
// clipped boxes + per-query metadata.
// ---------------------------------------------------------------------------
__global__ __launch_bounds__(1024) void mdh_topk_kernel(
    const float* __restrict__ cls,
    unsigned int* __restrict__ keys_ws,
    const float* __restrict__ boxes,
    const int* __restrict__ hptr,
    const int* __restrict__ wptr,
    float* __restrict__ out,
    float* __restrict__ ws_val,
    int* __restrict__ ws_qidx,
    float* __restrict__ ws_area,
    ull* __restrict__ acc_sig,
    unsigned int* __restrict__ acc_cnt,
    unsigned int* __restrict__ done)
{
    const int b = blockIdx.x;
    const int tid = threadIdx.x;
    const int N = QQ * CC;   // 24000
    const float* __restrict__ lg = cls + (size_t)b * N;
    unsigned int* __restrict__ keys = keys_ws + (size_t)b * N;

    __shared__ int hist[2048];
    __shared__ int chunkSum[256];
    __shared__ unsigned int sh_prefix;
    __shared__ int sh_krem;
    __shared__ int cntG, cntE;
    __shared__ float gV[128];
    __shared__ int gI[128];
    __shared__ int eI[256];
    __shared__ int fIdx[KK];
    __shared__ float fVal[KK];

    // zero accumulators + done counters (ws poisoned 0xAA once, not re-poisoned)
    if (tid < KK) {
        acc_sig[b * KK + tid] = 0ull;
        acc_cnt[b * KK + tid] = 0u;
        done[b * KK + tid] = 0u;
    }

    unsigned int prefix = 0u;
    int krem = KK;

    // ---- round 0: compute keys + 11-bit hist ----
    for (int t = tid; t < 2048; t += 1024) hist[t] = 0;
    __syncthreads();
    for (int i = tid; i < N; i += 1024) {
        float s = 1.0f / (1.0f + expf(-lg[i]));
        unsigned int key = __float_as_uint(s);
        keys[i] = key;
        atomicAdd(&hist[key >> 21], 1);
    }
    __syncthreads();
    {
        int cs = 0;
        if (tid < 256) {
            #pragma unroll
            for (int j = 0; j < 8; ++j) cs += hist[tid * 8 + j];
            chunkSum[tid] = cs;
        }
        __syncthreads();
        if (tid == 0) {
            int acc = 0, sel = 0;
            for (int c = 255; c >= 0; --c) {
                if (acc + chunkSum[c] >= krem) {
                    for (int bin = c * 8 + 7; bin >= c * 8; --bin) {
                        int h2 = hist[bin];
                        if (acc + h2 >= krem) { sel = bin; break; }
                        acc += h2;
                    }
                    break;
                }
                acc += chunkSum[c];
            }
            sh_prefix = (unsigned int)sel << 21;
            sh_krem = krem - acc;
        }
        __syncthreads();
        prefix = sh_prefix;
        krem = sh_krem;
        __syncthreads();
    }

    // ---- rounds 1,2 on cached keys ----
    #pragma unroll
    for (int round = 1; round < 3; ++round) {
        const int shift = (round == 1) ? 10 : 0;
        const int nbits = (round == 1) ? 11 : 10;
        const unsigned int binmask = (1u << nbits) - 1u;
        const unsigned int hmask = 0xFFFFFFFFu << (shift + nbits);

        for (int t = tid; t < 2048; t += 1024) hist[t] = 0;
        __syncthreads();
        for (int i = tid * 4; i < N; i += 4096) {
            uint4 kv = *(const uint4*)(keys + i);
            unsigned int ka[4] = {kv.x, kv.y, kv.z, kv.w};
            #pragma unroll
            for (int j = 0; j < 4; ++j) {
                if ((ka[j] & hmask) == (prefix & hmask))
                    atomicAdd(&hist[(ka[j] >> shift) & binmask], 1);
            }
        }
        __syncthreads();
        int cs = 0;
        if (tid < 256) {
            #pragma unroll
            for (int j = 0; j < 8; ++j) cs += hist[tid * 8 + j];
            chunkSum[tid] = cs;
        }
        __syncthreads();
        if (tid == 0) {
            int acc = 0, sel = 0;
            for (int c = 255; c >= 0; --c) {
                if (acc + chunkSum[c] >= krem) {
                    for (int bin = c * 8 + 7; bin >= c * 8; --bin) {
                        int h2 = hist[bin];
                        if (acc + h2 >= krem) { sel = bin; break; }
                        acc += h2;
                    }
                    break;
                }
                acc += chunkSum[c];
            }
            sh_prefix = prefix | ((unsigned int)sel << shift);
            sh_krem = krem - acc;
        }
        __syncthreads();
        prefix = sh_prefix;
        krem = sh_krem;
        __syncthreads();
    }

    // ---- collect: >T (winners) and ==T (tie candidates) ----
    const unsigned int T = prefix;   // exact key of the 100th-largest
    if (tid == 0) { cntG = 0; cntE = 0; }
    __syncthreads();
    for (int i = tid * 4; i < N; i += 4096) {
        uint4 kv = *(const uint4*)(keys + i);
        unsigned int ka[4] = {kv.x, kv.y, kv.z, kv.w};
        #pragma unroll
        for (int j = 0; j < 4; ++j) {
            unsigned int key = ka[j];
            if (key > T) {
                int p = atomicAdd(&cntG, 1);
                if (p < 128) { gV[p] = __uint_as_float(key); gI[p] = i + j; }
            } else if (key == T) {
                int p = atomicAdd(&cntE, 1);
                if (p < 256) eI[p] = i + j;
            }
        }
    }
    __syncthreads();
    const int nG = min(cntG, 128);   // == 100 - krem by construction (<=99)
    const int nE = min(cntE, 256);

    if (tid < nG) {
        float v = gV[tid]; int idx = gI[tid];
        int r = 0;
        for (int j = 0; j < nG; ++j) {
            float vj = gV[j]; int ij = gI[j];
            if (vj > v || (vj == v && ij < idx)) ++r;
        }
        if (r < KK) { fIdx[r] = idx; fVal[r] = v; }
    }
    if (tid < nE) {
        int idx = eI[tid];
        int r = 0;
        for (int j = 0; j < nE; ++j) if (eI[j] < idx) ++r;
        if (r < krem && (nG + r) < KK) { fIdx[nG + r] = idx; fVal[nG + r] = __uint_as_float(T); }
    }
    __syncthreads();

    const int h = *hptr, w = *wptr;
    const float fw = (float)w, fh = (float)h;
    if (tid < KK) {
        int idx = fIdx[tid];
        float val = fVal[tid];
        int q = idx / CC;
        int label = idx - q * CC;
        int o = b * KK + tid;
        out[BB * KK * 5 + o] = (float)label;               // labels chunk
        const float* bx = boxes + ((size_t)(b * QQ + q)) * 4;
        float cx = bx[0], cy = bx[1], bw = bx[2], bh = bx[3];
        float x1 = fminf(fmaxf((cx - bw * 0.5f) * fw, 0.0f), fw - 1.0f);
        float y1 = fminf(fmaxf((cy - bh * 0.5f) * fh, 0.0f), fh - 1.0f);
        float x2 = fminf(fmaxf((cx + bw * 0.5f) * fw, 0.0f), fw - 1.0f);
        float y2 = fminf(fmaxf((cy + bh * 0.5f) * fh, 0.0f), fh - 1.0f);
        float* br = out + (size_t)o * 5;
        br[0] = x1; br[1] = y1; br[2] = x2; br[3] = y2;    // boxes_scores[:,0:4]
        ws_val[o] = val;
        ws_qidx[o] = q;
        ws_area[o] = (x2 - x1) * (y2 - y1);
    }
}

// ---------------------------------------------------------------------------
// Kernel B (specialized h=w=800): each thread computes a 4x4 output tile from
// a 3x3 source neighborhood with compile-time weights. PLAIN float4 stores
// this round (A/B vs round-3 nt stores: fillBuffer proves the L2-writeback
// store path reaches ~6.8 TB/s). 1D grid with XCD-chunked bijective swizzle.
// Last-arriving block per bq computes obj/score/keep (fused final kernel).
// Grid: 200 * 157 = 31400 blocks.
// ---------------------------------------------------------------------------
__global__ __launch_bounds__(256) void mdh_masks800_kernel(
    const float* __restrict__ mp,
    const int* __restrict__ ws_qidx,
    const float* __restrict__ ws_val,
    const float* __restrict__ ws_area,
    float* __restrict__ out,
    ull* __restrict__ acc_sig,
    unsigned int* __restrict__ acc_cnt,
    unsigned int* __restrict__ done)
{
    // XCD-chunked bijective swizzle (31400 % 8 == 0, 31400/8 = 3925)
    const int orig = blockIdx.x;
    const int wg = (orig & 7) * 3925 + (orig >> 3);
    const int bq = wg / 157;              // compile-time const divisor
    const int chunk = wg - bq * 157;

    const int b = bq / KK;
    const int q = ws_qidx[bq];
    const float* __restrict__ src = mp + ((size_t)(b * QQ + q)) * (HM * WM);
    float* __restrict__ out_masks = out + BB * KK * 6;

    const int t = chunk * 256 + threadIdx.x;
    float ssum = 0.0f;
    int scnt = 0;

    if (t < HM * WM) {
        const int m = t / WM;             // div by constant -> mul_hi
        const int k = t - m * WM;
        const int rm1 = (m > 0 ? m - 1 : 0) * WM;
        const int r0  = m * WM;
        const int rp1 = (m < HM - 1 ? m + 1 : HM - 1) * WM;
        const int cm1 = (k > 0 ? k - 1 : 0);
        const int cp1 = (k < WM - 1 ? k + 1 : WM - 1);

        float a0m = src[rm1 + cm1], a00 = src[rm1 + k], a0p = src[rm1 + cp1];
        float a1m = src[r0  + cm1], a10 = src[r0  + k], a1p = src[r0  + cp1];
        float a2m = src[rp1 + cm1], a20 = src[rp1 + k], a2p = src[rp1 + cp1];

        float* dst = out_masks + (size_t)bq * 640000 + (size_t)(4 * m) * 800 + 4 * k;

        #pragma unroll
        for (int r = 0; r < 4; ++r) {
            float um, u0, up;
            if (r == 0)      { um = 0.375f*a0m + 0.625f*a1m; u0 = 0.375f*a00 + 0.625f*a10; up = 0.375f*a0p + 0.625f*a1p; }
            else if (r == 1) { um = 0.125f*a0m + 0.875f*a1m; u0 = 0.125f*a00 + 0.875f*a10; up = 0.125f*a0p + 0.875f*a1p; }
            else if (r == 2) { um = 0.875f*a1m + 0.125f*a2m; u0 = 0.875f*a10 + 0.125f*a20; up = 0.875f*a1p + 0.125f*a2p; }
            else             { um = 0.625f*a1m + 0.375f*a2m; u0 = 0.625f*a10 + 0.375f*a20; up = 0.625f*a1p + 0.375f*a2p; }

            float pmv[4];
            pmv[0] = 0.375f * um + 0.625f * u0;
            pmv[1] = 0.125f * um + 0.875f * u0;
            pmv[2] = 0.875f * u0 + 0.125f * up;
            pmv[3] = 0.625f * u0 + 0.375f * up;

            f32x4 ov;
            #pragma unroll
            for (int j = 0; j < 4; ++j) {
                bool pos = pmv[j] > 0.0f;
                ov[j] = pos ? 1.0f : 0.0f;
                if (pos) { ssum += 1.0f / (1.0f + __expf(-pmv[j])); scnt++; }
            }
            *(f32x4*)(dst + r * 800) = ov;    // plain store (A/B vs nt)
        }
    }

    // deterministic block reduction (fixed order), one atomic pair per block
    for (int off = 32; off > 0; off >>= 1) {
        ssum += __shfl_down(ssum, off);
        scnt += __shfl_down(scnt, off);
    }
    __shared__ float wsum[4];
    __shared__ int wcnt[4];
    const int wid = threadIdx.x >> 6;
    const int lane = threadIdx.x & 63;
    if (lane == 0) { wsum[wid] = ssum; wcnt[wid] = scnt; }
    __syncthreads();
    if (threadIdx.x == 0) {
        float tt = wsum[0] + wsum[1] + wsum[2] + wsum[3];
        int c = wcnt[0] + wcnt[1] + wcnt[2] + wcnt[3];
        if (c > 0) {
            // fixed-point 2^32 accumulate -> bit-deterministic across replays
            atomicAdd(&acc_sig[bq], (ull)((double)tt * 4294967296.0 + 0.5));
            atomicAdd(&acc_cnt[bq], (unsigned int)c);
        }
        __threadfence();                       // acc atomics visible before done++
        unsigned int old = atomicAdd(&done[bq], 1u);
        if (old == 156u) {                     // last of 157 blocks for this bq
            __threadfence();
            ull sig_fp = atomicAdd(&acc_sig[bq], 0ull);       // atomic read
            unsigned int cnt = atomicAdd(&acc_cnt[bq], 0u);   // atomic read
            float sig = (float)((double)sig_fp * (1.0 / 4294967296.0));
            float obj = sig / ((float)cnt + 1e-6f);
            float ps = ws_val[bq] * obj;
            out[(size_t)bq * 5 + 4] = ps;
            bool keep = (cnt > 5u) && (ws_area[bq] > 10.0f) && (ps > 0.05f);
            out[(size_t)(BB * KK * 6) + (size_t)BB * KK * 640000 + bq] = keep ? 1.0f : 0.0f;
        }
    }
}

// ---------------------------------------------------------------------------
// Kernel B-generic: fallback for pix != 640000 (unused for this problem).
// ---------------------------------------------------------------------------
__global__ __launch_bounds__(256) void mdh_masks_kernel(
    const float* __restrict__ mp,
    const int* __restrict__ ws_qidx,
    const int* __restrict__ hptr,
    const int* __restrict__ wptr,
    float* __restrict__ out_masks,
    ull* __restrict__ acc_sig,
    unsigned int* __restrict__ acc_cnt)
{
    const int bq = blockIdx.y;
    const int b = bq / KK;
    const int q = ws_qidx[bq];
    const int h = *hptr, w = *wptr;
    const long long pix = (long long)h * w;
    const float* __restrict__ src = mp + ((size_t)(b * QQ + q)) * (HM * WM);
    const float sy = (float)HM / (float)h;
    const float sx = (float)WM / (float)w;

    const long long p0 = (long long)blockIdx.x * 1024 + (long long)threadIdx.x * 4;
    float ssum = 0.0f;
    int scnt = 0;
    if (p0 < pix) {
        float pmv[4];
        for (int j = 0; j < 4; ++j) {
            long long p = p0 + j;
            if (p >= pix) { pmv[j] = -1.0f; continue; }
            int yy = (int)(p / w);
            int xx = (int)(p - (long long)yy * w);
            float yi = ((float)yy + 0.5f) * sy - 0.5f;
            float rf = floorf(yi); float fy = yi - rf;
            int r0 = max((int)rf, 0); int r1 = min((int)rf + 1, HM - 1);
            float xi = ((float)xx + 0.5f) * sx - 0.5f;
            float cf = floorf(xi); float fx = xi - cf;
            int c0 = max((int)cf, 0); int c1 = min((int)cf + 1, WM - 1);
            float a  = src[r0 * WM + c0], b2 = src[r0 * WM + c1];
            float c  = src[r1 * WM + c0], d2 = src[r1 * WM + c1];
            float t0 = (1.0f - fy) * a  + fy * c;
            float t1 = (1.0f - fy) * b2 + fy * d2;
            pmv[j] = (1.0f - fx) * t0 + fx * t1;
        }
        for (int j = 0; j < 4; ++j) {
            long long p = p0 + j;
            if (p >= pix) continue;
            bool pos = pmv[j] > 0.0f;
            out_masks[(size_t)bq * pix + p] = pos ? 1.0f : 0.0f;
            if (pos) { ssum += 1.0f / (1.0f + __expf(-pmv[j])); scnt++; }
        }
    }

    for (int off = 32; off > 0; off >>= 1) {
        ssum += __shfl_down(ssum, off);
        scnt += __shfl_down(scnt, off);
    }
    __shared__ float wsum[4];
    __shared__ int wcnt[4];
    const int wid = threadIdx.x >> 6;
    const int lane = threadIdx.x & 63;
    if (lane == 0) { wsum[wid] = ssum; wcnt[wid] = scnt; }
    __syncthreads();
    if (threadIdx.x == 0) {
        float tt = wsum[0] + wsum[1] + wsum[2] + wsum[3];
        int c = wcnt[0] + wcnt[1] + wcnt[2] + wcnt[3];
        if (c > 0) {
            atomicAdd(&acc_sig[bq], (ull)((double)tt * 4294967296.0 + 0.5));
            atomicAdd(&acc_cnt[bq], (unsigned int)c);
        }
    }
}

// ---------------------------------------------------------------------------
// Kernel C: final pass for the generic fallback path only.
// ---------------------------------------------------------------------------
__global__ void mdh_final_kernel(
    const ull* __restrict__ acc_sig,
    const unsigned int* __restrict__ acc_cnt,
    const float* __restrict__ ws_val,
    const float* __restrict__ ws_area,
    float* __restrict__ out,
    long long pix)
{
    int t = blockIdx.x * blockDim.x + threadIdx.x;
    if (t < BB * KK) {
        float sig = (float)((double)acc_sig[t] * (1.0 / 4294967296.0));
        unsigned int cnt = acc_cnt[t];
        float obj = sig / ((float)cnt + 1e-6f);
        float ps = ws_val[t] * obj;
        out[(size_t)t * 5 + 4] = ps;
        bool keep = (cnt > 5) && (ws_area[t] > 10.0f) && (ps > 0.05f);
        out[(size_t)(BB * KK * 5 + BB * KK) + (size_t)BB * KK * pix + t] = keep ? 1.0f : 0.0f;
    }
}

extern "C" void kernel_launch(void* const* d_in, const int* in_sizes, int n_in,
                              void* d_out, int out_size, void* d_ws, size_t ws_size,
                              hipStream_t stream)
{
    const float* mp    = (const float*)d_in[0];   // (B,Q,200,200) f32
    const float* cls   = (const float*)d_in[1];   // (B,Q,80) f32
    const float* boxes = (const float*)d_in[2];   // (B,Q,4) f32
    const int* hptr    = (const int*)d_in[3];     // scalar h
    const int* wptr    = (const int*)d_in[4];     // scalar w
    float* out = (float*)d_out;

    // out layout: boxes_scores (B*K*5) | labels (B*K) | masks (B*K*h*w) | keep (B*K)
    const long long pix = ((long long)out_size - (long long)BB * KK * 7) / ((long long)BB * KK);

    char* wsb = (char*)d_ws;
    ull* acc_sig          = (ull*)wsb;                       // 200*8    @0
    unsigned int* acc_cnt = (unsigned int*)(wsb + 1600);     // 200*4    @1600
    float* ws_val         = (float*)(wsb + 2400);            // 200*4    @2400
    int* ws_qidx          = (int*)(wsb + 3200);              // 200*4    @3200
    float* ws_area        = (float*)(wsb + 4000);            // 200*4    @4000
    unsigned int* ws_done = (unsigned int*)(wsb + 4800);     // 200*4    @4800
    unsigned int* ws_keys = (unsigned int*)(wsb + 5600);     // 48000*4  @5600 (16B aligned)

    mdh_topk_kernel<<<BB, 1024, 0, stream>>>(cls, ws_keys, boxes, hptr, wptr, out,
                                             ws_val, ws_qidx, ws_area,
                                             acc_sig, acc_cnt, ws_done);

    if (pix == 640000) {
        mdh_masks800_kernel<<<200 * 157, 256, 0, stream>>>(
            mp, ws_qidx, ws_val, ws_area, out, acc_sig, acc_cnt, ws_done);
    } else {
        const int nblk = (int)((pix + 1023) / 1024);
        mdh_masks_kernel<<<dim3(nblk, BB * KK), 256, 0, stream>>>(
            mp, ws_qidx, hptr, wptr, out + BB * KK * 6, acc_sig, acc_cnt);
        mdh_final_kernel<<<1, 256, 0, stream>>>(acc_sig, acc_cnt, ws_val, ws_area, out, pix);
    }
}

// Round 5
// 188.630 us; speedup vs baseline: 6.8177x; 6.8177x over previous
//
#include <hip/hip_runtime.h>

typedef unsigned long long ull;
typedef float f32x4 __attribute__((ext_vector_type(4)));

#define BB 2
#define QQ 300
#define CC 80
#define KK 100
#define HM 200
#define WM 200

// ---------------------------------------------------------------------------
// Kernel A: per-batch top-100 via 3-round radix select (11/11/10 bits) on
// sigmoid keys (float bits; all positive -> uint order == float order).
// Round 0 computes keys from logits (expf, bit-identical ordering to JAX's
// f32 sigmoid) and caches them in ws; rounds 1-2 + collect re-read cached
// keys. 1024 threads (16 waves). Exact JAX tie-break (value desc, index
// asc). Also zeroes per-query accumulators, writes labels + clipped boxes +
// per-query metadata.
// ---------------------------------------------------------------------------
__global__ __launch_bounds__(1024) void mdh_topk_kernel(
    const float* __restrict__ cls,
    unsigned int* __restrict__ keys_ws,
    const float* __restrict__ boxes,
    const int* __restrict__ hptr,
    const int* __restrict__ wptr,
    float* __restrict__ out,
    float* __restrict__ ws_val,
    int* __restrict__ ws_qidx,
    float* __restrict__ ws_area,
    ull* __restrict__ acc_sig,
    unsigned int* __restrict__ acc_cnt)
{
    const int b = blockIdx.x;
    const int tid = threadIdx.x;
    const int N = QQ * CC;   // 24000
    const float* __restrict__ lg = cls + (size_t)b * N;
    unsigned int* __restrict__ keys = keys_ws + (size_t)b * N;

    __shared__ int hist[2048];
    __shared__ int chunkSum[256];
    __shared__ unsigned int sh_prefix;
    __shared__ int sh_krem;
    __shared__ int cntG, cntE;
    __shared__ float gV[128];
    __shared__ int gI[128];
    __shared__ int eI[256];
    __shared__ int fIdx[KK];
    __shared__ float fVal[KK];

    // zero accumulators (ws is poisoned 0xAA once, never re-poisoned)
    if (tid < KK) {
        acc_sig[b * KK + tid] = 0ull;
        acc_cnt[b * KK + tid] = 0u;
    }

    unsigned int prefix = 0u;
    int krem = KK;

    // ---- round 0: compute keys + 11-bit hist ----
    for (int t = tid; t < 2048; t += 1024) hist[t] = 0;
    __syncthreads();
    for (int i = tid; i < N; i += 1024) {
        float s = 1.0f / (1.0f + expf(-lg[i]));
        unsigned int key = __float_as_uint(s);
        keys[i] = key;
        atomicAdd(&hist[key >> 21], 1);
    }
    __syncthreads();
    {
        int cs = 0;
        if (tid < 256) {
            #pragma unroll
            for (int j = 0; j < 8; ++j) cs += hist[tid * 8 + j];
            chunkSum[tid] = cs;
        }
        __syncthreads();
        if (tid == 0) {
            int acc = 0, sel = 0;
            for (int c = 255; c >= 0; --c) {
                if (acc + chunkSum[c] >= krem) {
                    for (int bin = c * 8 + 7; bin >= c * 8; --bin) {
                        int h2 = hist[bin];
                        if (acc + h2 >= krem) { sel = bin; break; }
                        acc += h2;
                    }
                    break;
                }
                acc += chunkSum[c];
            }
            sh_prefix = (unsigned int)sel << 21;
            sh_krem = krem - acc;
        }
        __syncthreads();
        prefix = sh_prefix;
        krem = sh_krem;
        __syncthreads();
    }

    // ---- rounds 1,2 on cached keys ----
    #pragma unroll
    for (int round = 1; round < 3; ++round) {
        const int shift = (round == 1) ? 10 : 0;
        const int nbits = (round == 1) ? 11 : 10;
        const unsigned int binmask = (1u << nbits) - 1u;
        const unsigned int hmask = 0xFFFFFFFFu << (shift + nbits);

        for (int t = tid; t < 2048; t += 1024) hist[t] = 0;
        __syncthreads();
        for (int i = tid * 4; i < N; i += 4096) {
            uint4 kv = *(const uint4*)(keys + i);
            unsigned int ka[4] = {kv.x, kv.y, kv.z, kv.w};
            #pragma unroll
            for (int j = 0; j < 4; ++j) {
                if ((ka[j] & hmask) == (prefix & hmask))
                    atomicAdd(&hist[(ka[j] >> shift) & binmask], 1);
            }
        }
        __syncthreads();
        int cs = 0;
        if (tid < 256) {
            #pragma unroll
            for (int j = 0; j < 8; ++j) cs += hist[tid * 8 + j];
            chunkSum[tid] = cs;
        }
        __syncthreads();
        if (tid == 0) {
            int acc = 0, sel = 0;
            for (int c = 255; c >= 0; --c) {
                if (acc + chunkSum[c] >= krem) {
                    for (int bin = c * 8 + 7; bin >= c * 8; --bin) {
                        int h2 = hist[bin];
                        if (acc + h2 >= krem) { sel = bin; break; }
                        acc += h2;
                    }
                    break;
                }
                acc += chunkSum[c];
            }
            sh_prefix = prefix | ((unsigned int)sel << shift);
            sh_krem = krem - acc;
        }
        __syncthreads();
        prefix = sh_prefix;
        krem = sh_krem;
        __syncthreads();
    }

    // ---- collect: >T (winners) and ==T (tie candidates) ----
    const unsigned int T = prefix;   // exact key of the 100th-largest
    if (tid == 0) { cntG = 0; cntE = 0; }
    __syncthreads();
    for (int i = tid * 4; i < N; i += 4096) {
        uint4 kv = *(const uint4*)(keys + i);
        unsigned int ka[4] = {kv.x, kv.y, kv.z, kv.w};
        #pragma unroll
        for (int j = 0; j < 4; ++j) {
            unsigned int key = ka[j];
            if (key > T) {
                int p = atomicAdd(&cntG, 1);
                if (p < 128) { gV[p] = __uint_as_float(key); gI[p] = i + j; }
            } else if (key == T) {
                int p = atomicAdd(&cntE, 1);
                if (p < 256) eI[p] = i + j;
            }
        }
    }
    __syncthreads();
    const int nG = min(cntG, 128);   // == 100 - krem by construction (<=99)
    const int nE = min(cntE, 256);

    if (tid < nG) {
        float v = gV[tid]; int idx = gI[tid];
        int r = 0;
        for (int j = 0; j < nG; ++j) {
            float vj = gV[j]; int ij = gI[j];
            if (vj > v || (vj == v && ij < idx)) ++r;
        }
        if (r < KK) { fIdx[r] = idx; fVal[r] = v; }
    }
    if (tid < nE) {
        int idx = eI[tid];
        int r = 0;
        for (int j = 0; j < nE; ++j) if (eI[j] < idx) ++r;
        if (r < krem && (nG + r) < KK) { fIdx[nG + r] = idx; fVal[nG + r] = __uint_as_float(T); }
    }
    __syncthreads();

    const int h = *hptr, w = *wptr;
    const float fw = (float)w, fh = (float)h;
    if (tid < KK) {
        int idx = fIdx[tid];
        float val = fVal[tid];
        int q = idx / CC;
        int label = idx - q * CC;
        int o = b * KK + tid;
        out[BB * KK * 5 + o] = (float)label;               // labels chunk
        const float* bx = boxes + ((size_t)(b * QQ + q)) * 4;
        float cx = bx[0], cy = bx[1], bw = bx[2], bh = bx[3];
        float x1 = fminf(fmaxf((cx - bw * 0.5f) * fw, 0.0f), fw - 1.0f);
        float y1 = fminf(fmaxf((cy - bh * 0.5f) * fh, 0.0f), fh - 1.0f);
        float x2 = fminf(fmaxf((cx + bw * 0.5f) * fw, 0.0f), fw - 1.0f);
        float y2 = fminf(fmaxf((cy + bh * 0.5f) * fh, 0.0f), fh - 1.0f);
        float* br = out + (size_t)o * 5;
        br[0] = x1; br[1] = y1; br[2] = x2; br[3] = y2;    // boxes_scores[:,0:4]
        ws_val[o] = val;
        ws_qidx[o] = q;
        ws_area[o] = (x2 - x1) * (y2 - y1);
    }
}

// ---------------------------------------------------------------------------
// Kernel B (specialized h=w=800): each thread computes a 4x4 output tile from
// a 3x3 source neighborhood with compile-time weights. Round-3 structure
// (no fences, no done counters, separate final kernel); SINGLE change vs
// round 3: plain float4 stores instead of nontemporal (A/B — fillBuffer
// proves the L2-writeback store path reaches ~6.8 TB/s; nt gave 4.2).
// 1D grid with XCD-chunked bijective swizzle (FETCH 15 MB in round 4 proves
// the swizzle gives near-ideal read locality).
// Grid: 200 * 157 = 31400 blocks.
// ---------------------------------------------------------------------------
__global__ __launch_bounds__(256) void mdh_masks800_kernel(
    const float* __restrict__ mp,
    const int* __restrict__ ws_qidx,
    float* __restrict__ out_masks,
    ull* __restrict__ acc_sig,
    unsigned int* __restrict__ acc_cnt)
{
    // XCD-chunked bijective swizzle (31400 % 8 == 0, 31400/8 = 3925)
    const int orig = blockIdx.x;
    const int wg = (orig & 7) * 3925 + (orig >> 3);
    const int bq = wg / 157;              // compile-time const divisor
    const int chunk = wg - bq * 157;

    const int b = bq / KK;
    const int q = ws_qidx[bq];
    const float* __restrict__ src = mp + ((size_t)(b * QQ + q)) * (HM * WM);

    const int t = chunk * 256 + threadIdx.x;
    float ssum = 0.0f;
    int scnt = 0;

    if (t < HM * WM) {
        const int m = t / WM;             // div by constant -> mul_hi
        const int k = t - m * WM;
        const int rm1 = (m > 0 ? m - 1 : 0) * WM;
        const int r0  = m * WM;
        const int rp1 = (m < HM - 1 ? m + 1 : HM - 1) * WM;
        const int cm1 = (k > 0 ? k - 1 : 0);
        const int cp1 = (k < WM - 1 ? k + 1 : WM - 1);

        float a0m = src[rm1 + cm1], a00 = src[rm1 + k], a0p = src[rm1 + cp1];
        float a1m = src[r0  + cm1], a10 = src[r0  + k], a1p = src[r0  + cp1];
        float a2m = src[rp1 + cm1], a20 = src[rp1 + k], a2p = src[rp1 + cp1];

        float* dst = out_masks + (size_t)bq * 640000 + (size_t)(4 * m) * 800 + 4 * k;

        #pragma unroll
        for (int r = 0; r < 4; ++r) {
            float um, u0, up;
            if (r == 0)      { um = 0.375f*a0m + 0.625f*a1m; u0 = 0.375f*a00 + 0.625f*a10; up = 0.375f*a0p + 0.625f*a1p; }
            else if (r == 1) { um = 0.125f*a0m + 0.875f*a1m; u0 = 0.125f*a00 + 0.875f*a10; up = 0.125f*a0p + 0.875f*a1p; }
            else if (r == 2) { um = 0.875f*a1m + 0.125f*a2m; u0 = 0.875f*a10 + 0.125f*a20; up = 0.875f*a1p + 0.125f*a2p; }
            else             { um = 0.625f*a1m + 0.375f*a2m; u0 = 0.625f*a10 + 0.375f*a20; up = 0.625f*a1p + 0.375f*a2p; }

            float pmv[4];
            pmv[0] = 0.375f * um + 0.625f * u0;
            pmv[1] = 0.125f * um + 0.875f * u0;
            pmv[2] = 0.875f * u0 + 0.125f * up;
            pmv[3] = 0.625f * u0 + 0.375f * up;

            f32x4 ov;
            #pragma unroll
            for (int j = 0; j < 4; ++j) {
                bool pos = pmv[j] > 0.0f;
                ov[j] = pos ? 1.0f : 0.0f;
                if (pos) { ssum += 1.0f / (1.0f + __expf(-pmv[j])); scnt++; }
            }
            *(f32x4*)(dst + r * 800) = ov;    // plain store (A/B vs round-3 nt)
        }
    }

    // deterministic block reduction (fixed order), one atomic pair per block
    for (int off = 32; off > 0; off >>= 1) {
        ssum += __shfl_down(ssum, off);
        scnt += __shfl_down(scnt, off);
    }
    __shared__ float wsum[4];
    __shared__ int wcnt[4];
    const int wid = threadIdx.x >> 6;
    const int lane = threadIdx.x & 63;
    if (lane == 0) { wsum[wid] = ssum; wcnt[wid] = scnt; }
    __syncthreads();
    if (threadIdx.x == 0) {
        float tt = wsum[0] + wsum[1] + wsum[2] + wsum[3];
        int c = wcnt[0] + wcnt[1] + wcnt[2] + wcnt[3];
        if (c > 0) {
            // fixed-point 2^32 accumulate -> bit-deterministic across replays
            atomicAdd(&acc_sig[bq], (ull)((double)tt * 4294967296.0 + 0.5));
            atomicAdd(&acc_cnt[bq], (unsigned int)c);
        }
    }
}

// ---------------------------------------------------------------------------
// Kernel B-generic: fallback for pix != 640000 (unused for this problem).
// ---------------------------------------------------------------------------
__global__ __launch_bounds__(256) void mdh_masks_kernel(
    const float* __restrict__ mp,
    const int* __restrict__ ws_qidx,
    const int* __restrict__ hptr,
    const int* __restrict__ wptr,
    float* __restrict__ out_masks,
    ull* __restrict__ acc_sig,
    unsigned int* __restrict__ acc_cnt)
{
    const int bq = blockIdx.y;
    const int b = bq / KK;
    const int q = ws_qidx[bq];
    const int h = *hptr, w = *wptr;
    const long long pix = (long long)h * w;
    const float* __restrict__ src = mp + ((size_t)(b * QQ + q)) * (HM * WM);
    const float sy = (float)HM / (float)h;
    const float sx = (float)WM / (float)w;

    const long long p0 = (long long)blockIdx.x * 1024 + (long long)threadIdx.x * 4;
    float ssum = 0.0f;
    int scnt = 0;
    if (p0 < pix) {
        float pmv[4];
        for (int j = 0; j < 4; ++j) {
            long long p = p0 + j;
            if (p >= pix) { pmv[j] = -1.0f; continue; }
            int yy = (int)(p / w);
            int xx = (int)(p - (long long)yy * w);
            float yi = ((float)yy + 0.5f) * sy - 0.5f;
            float rf = floorf(yi); float fy = yi - rf;
            int r0 = max((int)rf, 0); int r1 = min((int)rf + 1, HM - 1);
            float xi = ((float)xx + 0.5f) * sx - 0.5f;
            float cf = floorf(xi); float fx = xi - cf;
            int c0 = max((int)cf, 0); int c1 = min((int)cf + 1, WM - 1);
            float a  = src[r0 * WM + c0], b2 = src[r0 * WM + c1];
            float c  = src[r1 * WM + c0], d2 = src[r1 * WM + c1];
            float t0 = (1.0f - fy) * a  + fy * c;
            float t1 = (1.0f - fy) * b2 + fy * d2;
            pmv[j] = (1.0f - fx) * t0 + fx * t1;
        }
        for (int j = 0; j < 4; ++j) {
            long long p = p0 + j;
            if (p >= pix) continue;
            bool pos = pmv[j] > 0.0f;
            out_masks[(size_t)bq * pix + p] = pos ? 1.0f : 0.0f;
            if (pos) { ssum += 1.0f / (1.0f + __expf(-pmv[j])); scnt++; }
        }
    }

    for (int off = 32; off > 0; off >>= 1) {
        ssum += __shfl_down(ssum, off);
        scnt += __shfl_down(scnt, off);
    }
    __shared__ float wsum[4];
    __shared__ int wcnt[4];
    const int wid = threadIdx.x >> 6;
    const int lane = threadIdx.x & 63;
    if (lane == 0) { wsum[wid] = ssum; wcnt[wid] = scnt; }
    __syncthreads();
    if (threadIdx.x == 0) {
        float tt = wsum[0] + wsum[1] + wsum[2] + wsum[3];
        int c = wcnt[0] + wcnt[1] + wcnt[2] + wcnt[3];
        if (c > 0) {
            atomicAdd(&acc_sig[bq], (ull)((double)tt * 4294967296.0 + 0.5));
            atomicAdd(&acc_cnt[bq], (unsigned int)c);
        }
    }
}

// ---------------------------------------------------------------------------
// Kernel C: obj = sig_sum / (count + 1e-6); pred_score; keep flags.
// ---------------------------------------------------------------------------
__global__ void mdh_final_kernel(
    const ull* __restrict__ acc_sig,
    const unsigned int* __restrict__ acc_cnt,
    const float* __restrict__ ws_val,
    const float* __restrict__ ws_area,
    float* __restrict__ out,
    long long pix)
{
    int t = blockIdx.x * blockDim.x + threadIdx.x;
    if (t < BB * KK) {
        float sig = (float)((double)acc_sig[t] * (1.0 / 4294967296.0));
        unsigned int cnt = acc_cnt[t];
        float obj = sig / ((float)cnt + 1e-6f);
        float ps = ws_val[t] * obj;
        out[(size_t)t * 5 + 4] = ps;
        bool keep = (cnt > 5) && (ws_area[t] > 10.0f) && (ps > 0.05f);
        out[(size_t)(BB * KK * 5 + BB * KK) + (size_t)BB * KK * pix + t] = keep ? 1.0f : 0.0f;
    }
}

extern "C" void kernel_launch(void* const* d_in, const int* in_sizes, int n_in,
                              void* d_out, int out_size, void* d_ws, size_t ws_size,
                              hipStream_t stream)
{
    const float* mp    = (const float*)d_in[0];   // (B,Q,200,200) f32
    const float* cls   = (const float*)d_in[1];   // (B,Q,80) f32
    const float* boxes = (const float*)d_in[2];   // (B,Q,4) f32
    const int* hptr    = (const int*)d_in[3];     // scalar h
    const int* wptr    = (const int*)d_in[4];     // scalar w
    float* out = (float*)d_out;

    // out layout: boxes_scores (B*K*5) | labels (B*K) | masks (B*K*h*w) | keep (B*K)
    const long long pix = ((long long)out_size - (long long)BB * KK * 7) / ((long long)BB * KK);

    char* wsb = (char*)d_ws;
    ull* acc_sig          = (ull*)wsb;                       // 200*8   @0
    unsigned int* acc_cnt = (unsigned int*)(wsb + 1600);     // 200*4   @1600
    float* ws_val         = (float*)(wsb + 2400);            // 200*4   @2400
    int* ws_qidx          = (int*)(wsb + 3200);              // 200*4   @3200
    float* ws_area        = (float*)(wsb + 4000);            // 200*4   @4000
    unsigned int* ws_keys = (unsigned int*)(wsb + 4800);     // 48000*4 @4800 (16B aligned)

    mdh_topk_kernel<<<BB, 1024, 0, stream>>>(cls, ws_keys, boxes, hptr, wptr, out,
                                             ws_val, ws_qidx, ws_area, acc_sig, acc_cnt);

    if (pix == 640000) {
        mdh_masks800_kernel<<<200 * 157, 256, 0, stream>>>(
            mp, ws_qidx, out + BB * KK * 6, acc_sig, acc_cnt);
    } else {
        const int nblk = (int)((pix + 1023) / 1024);
        mdh_masks_kernel<<<dim3(nblk, BB * KK), 256, 0, stream>>>(
            mp, ws_qidx, hptr, wptr, out + BB * KK * 6, acc_sig, acc_cnt);
    }

    mdh_final_kernel<<<1, 256, 0, stream>>>(acc_sig, acc_cnt, ws_val, ws_area, out, pix);
}

// Round 6
// 129.097 us; speedup vs baseline: 9.9617x; 1.4611x over previous
//
#include <hip/hip_runtime.h>

typedef unsigned long long ull;
typedef float f32x4 __attribute__((ext_vector_type(4)));

#define BB 2
#define QQ 300
#define CC 80
#define KK 100
#define HM 200
#define WM 200

// ---------------------------------------------------------------------------
// Parallel descending bin-select: given hist[2048] (only bins < nbins used),
// find bin `sel` (scanning from high to low) where the cumulative count
// reaches krem, and the count `acc` strictly above it. Threads 0..255 build
// 8-bin chunk sums; wave 0 suffix-scans 64 groups of 4 chunks via shfl;
// the unique crossing lane resolves chunk then bin. Caller must have
// __syncthreads()'d after filling hist. Leaves result in *sh_sel / *sh_acc
// (call __syncthreads() after).
// ---------------------------------------------------------------------------
__device__ __forceinline__ void bin_select_desc(
    const int* hist, int* chunkSum, int krem,
    int* sh_sel, int* sh_acc)
{
    const int tid = threadIdx.x;
    if (tid < 256) {
        int cs = 0;
        #pragma unroll
        for (int j = 0; j < 8; ++j) cs += hist[tid * 8 + j];
        chunkSum[tid] = cs;
    }
    __syncthreads();
    if (tid < 64) {
        const int l = tid;
        int s0 = chunkSum[4 * l + 0];
        int s1 = chunkSum[4 * l + 1];
        int s2 = chunkSum[4 * l + 2];
        int s3 = chunkSum[4 * l + 3];
        int sum4 = s0 + s1 + s2 + s3;
        int S = sum4;
        #pragma unroll
        for (int d = 1; d < 64; d <<= 1) {
            int up = __shfl_down(S, d);
            if (l + d < 64) S += up;
        }
        int Sn = __shfl_down(S, 1);               // S[l+1] (excl suffix)
        bool crossing = (S >= krem) && (l == 63 || Sn < krem);
        if (crossing) {
            int acc = S - sum4;                   // count above this 4-chunk group
            // narrow to chunk
            int c = 4 * l + 3;
            int cvals[4] = {s0, s1, s2, s3};
            #pragma unroll
            for (int cc = 3; cc >= 0; --cc) {
                int cv = cvals[cc];
                if (acc + cv >= krem) { c = 4 * l + cc; goto chunk_found; }
                acc += cv;
            }
            chunk_found:
            int sel = c * 8;
            #pragma unroll
            for (int bin = 7; bin >= 0; --bin) {
                int h2 = hist[c * 8 + bin];
                if (acc + h2 >= krem) { sel = c * 8 + bin; break; }
                acc += h2;
            }
            *sh_sel = sel;
            *sh_acc = acc;
        }
    }
}

// ---------------------------------------------------------------------------
// Kernel A: per-batch top-100 via 3-round radix select (11/11/10 bits) on
// sigmoid keys (float bits; all positive -> uint order == float order).
// Round 0 computes keys (expf, bit-identical ordering to JAX f32 sigmoid),
// caches them in ws; rounds 1-2 + collect re-read cached keys. 1024 threads.
// Exact JAX tie-break (value desc, index asc). Zeroes per-query accumulators
// + done counters; writes labels + clipped boxes + per-query metadata.
// ---------------------------------------------------------------------------
__global__ __launch_bounds__(1024) void mdh_topk_kernel(
    const float* __restrict__ cls,
    unsigned int* __restrict__ keys_ws,
    const float* __restrict__ boxes,
    const int* __restrict__ hptr,
    const int* __restrict__ wptr,
    float* __restrict__ out,
    float* __restrict__ ws_val,
    int* __restrict__ ws_qidx,
    float* __restrict__ ws_area,
    ull* __restrict__ acc_sig,
    unsigned int* __restrict__ acc_cnt,
    unsigned int* __restrict__ done)
{
    const int b = blockIdx.x;
    const int tid = threadIdx.x;
    const int N = QQ * CC;   // 24000
    const float* __restrict__ lg = cls + (size_t)b * N;
    unsigned int* __restrict__ keys = keys_ws + (size_t)b * N;

    __shared__ int hist[2048];
    __shared__ int chunkSum[256];
    __shared__ int sh_sel;
    __shared__ int sh_acc;
    __shared__ int cntG, cntE;
    __shared__ float gV[128];
    __shared__ int gI[128];
    __shared__ int eI[256];
    __shared__ int fIdx[KK];
    __shared__ float fVal[KK];

    // zero accumulators + done counters (ws poisoned 0xAA once, not re-poisoned)
    if (tid < KK) {
        acc_sig[b * KK + tid] = 0ull;
        acc_cnt[b * KK + tid] = 0u;
        done[b * KK + tid] = 0u;
    }

    unsigned int prefix = 0u;
    int krem = KK;

    // ---- round 0: compute keys + 11-bit hist (bits 31..21) ----
    for (int t = tid; t < 2048; t += 1024) hist[t] = 0;
    __syncthreads();
    for (int i = tid; i < N; i += 1024) {
        float s = 1.0f / (1.0f + expf(-lg[i]));
        unsigned int key = __float_as_uint(s);
        keys[i] = key;
        atomicAdd(&hist[key >> 21], 1);
    }
    __syncthreads();
    bin_select_desc(hist, chunkSum, krem, &sh_sel, &sh_acc);
    __syncthreads();
    prefix = (unsigned int)sh_sel << 21;
    krem = krem - sh_acc;
    __syncthreads();

    // ---- rounds 1,2 on cached keys ----
    #pragma unroll
    for (int round = 1; round < 3; ++round) {
        const int shift = (round == 1) ? 10 : 0;
        const int nbits = (round == 1) ? 11 : 10;
        const unsigned int binmask = (1u << nbits) - 1u;
        const unsigned int hmask = 0xFFFFFFFFu << (shift + nbits);

        for (int t = tid; t < 2048; t += 1024) hist[t] = 0;
        __syncthreads();
        for (int i = tid * 4; i < N; i += 4096) {
            uint4 kv = *(const uint4*)(keys + i);
            unsigned int ka[4] = {kv.x, kv.y, kv.z, kv.w};
            #pragma unroll
            for (int j = 0; j < 4; ++j) {
                if ((ka[j] & hmask) == (prefix & hmask))
                    atomicAdd(&hist[(ka[j] >> shift) & binmask], 1);
            }
        }
        __syncthreads();
        bin_select_desc(hist, chunkSum, krem, &sh_sel, &sh_acc);
        __syncthreads();
        prefix = prefix | ((unsigned int)sh_sel << shift);
        krem = krem - sh_acc;
        __syncthreads();
    }

    // ---- collect: >T (winners) and ==T (tie candidates) ----
    const unsigned int T = prefix;   // exact key of the 100th-largest
    if (tid == 0) { cntG = 0; cntE = 0; }
    __syncthreads();
    for (int i = tid * 4; i < N; i += 4096) {
        uint4 kv = *(const uint4*)(keys + i);
        unsigned int ka[4] = {kv.x, kv.y, kv.z, kv.w};
        #pragma unroll
        for (int j = 0; j < 4; ++j) {
            unsigned int key = ka[j];
            if (key > T) {
                int p = atomicAdd(&cntG, 1);
                if (p < 128) { gV[p] = __uint_as_float(key); gI[p] = i + j; }
            } else if (key == T) {
                int p = atomicAdd(&cntE, 1);
                if (p < 256) eI[p] = i + j;
            }
        }
    }
    __syncthreads();
    const int nG = min(cntG, 128);   // == 100 - krem by construction (<=99)
    const int nE = min(cntE, 256);

    if (tid < nG) {
        float v = gV[tid]; int idx = gI[tid];
        int r = 0;
        for (int j = 0; j < nG; ++j) {
            float vj = gV[j]; int ij = gI[j];
            if (vj > v || (vj == v && ij < idx)) ++r;
        }
        if (r < KK) { fIdx[r] = idx; fVal[r] = v; }
    }
    if (tid < nE) {
        int idx = eI[tid];
        int r = 0;
        for (int j = 0; j < nE; ++j) if (eI[j] < idx) ++r;
        if (r < krem && (nG + r) < KK) { fIdx[nG + r] = idx; fVal[nG + r] = __uint_as_float(T); }
    }
    __syncthreads();

    const int h = *hptr, w = *wptr;
    const float fw = (float)w, fh = (float)h;
    if (tid < KK) {
        int idx = fIdx[tid];
        float val = fVal[tid];
        int q = idx / CC;
        int label = idx - q * CC;
        int o = b * KK + tid;
        out[BB * KK * 5 + o] = (float)label;               // labels chunk
        const float* bx = boxes + ((size_t)(b * QQ + q)) * 4;
        float cx = bx[0], cy = bx[1], bw = bx[2], bh = bx[3];
        float x1 = fminf(fmaxf((cx - bw * 0.5f) * fw, 0.0f), fw - 1.0f);
        float y1 = fminf(fmaxf((cy - bh * 0.5f) * fh, 0.0f), fh - 1.0f);
        float x2 = fminf(fmaxf((cx + bw * 0.5f) * fw, 0.0f), fw - 1.0f);
        float y2 = fminf(fmaxf((cy + bh * 0.5f) * fh, 0.0f), fh - 1.0f);
        float* br = out + (size_t)o * 5;
        br[0] = x1; br[1] = y1; br[2] = x2; br[3] = y2;    // boxes_scores[:,0:4]
        ws_val[o] = val;
        ws_qidx[o] = q;
        ws_area[o] = (x2 - x1) * (y2 - y1);
    }
}

// ---------------------------------------------------------------------------
// Kernel B (specialized h=w=800): inner loop byte-identical to round 3
// (nontemporal float4 stores — A/B round 5 proved nt is +29 µs better;
// XCD-chunked swizzle gives FETCH ~15 MB). Added: last-arriving block per bq
// computes obj/score/keep. Ordering uses s_waitcnt vmcnt(0) (atomic->atomic
// ordering), NOT __threadfence (whose buffer_wbl2 caused round 4's 8x
// regression).
// Grid: 200 * 157 = 31400 blocks.
// ---------------------------------------------------------------------------
__global__ __launch_bounds__(256) void mdh_masks800_kernel(
    const float* __restrict__ mp,
    const int* __restrict__ ws_qidx,
    const float* __restrict__ ws_val,
    const float* __restrict__ ws_area,
    float* __restrict__ out,
    ull* __restrict__ acc_sig,
    unsigned int* __restrict__ acc_cnt,
    unsigned int* __restrict__ done)
{
    // XCD-chunked bijective swizzle (31400 % 8 == 0, 31400/8 = 3925)
    const int orig = blockIdx.x;
    const int wg = (orig & 7) * 3925 + (orig >> 3);
    const int bq = wg / 157;              // compile-time const divisor
    const int chunk = wg - bq * 157;

    const int b = bq / KK;
    const int q = ws_qidx[bq];
    const float* __restrict__ src = mp + ((size_t)(b * QQ + q)) * (HM * WM);
    float* __restrict__ out_masks = out + BB * KK * 6;

    const int t = chunk * 256 + threadIdx.x;
    float ssum = 0.0f;
    int scnt = 0;

    if (t < HM * WM) {
        const int m = t / WM;             // div by constant -> mul_hi
        const int k = t - m * WM;
        const int rm1 = (m > 0 ? m - 1 : 0) * WM;
        const int r0  = m * WM;
        const int rp1 = (m < HM - 1 ? m + 1 : HM - 1) * WM;
        const int cm1 = (k > 0 ? k - 1 : 0);
        const int cp1 = (k < WM - 1 ? k + 1 : WM - 1);

        float a0m = src[rm1 + cm1], a00 = src[rm1 + k], a0p = src[rm1 + cp1];
        float a1m = src[r0  + cm1], a10 = src[r0  + k], a1p = src[r0  + cp1];
        float a2m = src[rp1 + cm1], a20 = src[rp1 + k], a2p = src[rp1 + cp1];

        float* dst = out_masks + (size_t)bq * 640000 + (size_t)(4 * m) * 800 + 4 * k;

        #pragma unroll
        for (int r = 0; r < 4; ++r) {
            float um, u0, up;
            if (r == 0)      { um = 0.375f*a0m + 0.625f*a1m; u0 = 0.375f*a00 + 0.625f*a10; up = 0.375f*a0p + 0.625f*a1p; }
            else if (r == 1) { um = 0.125f*a0m + 0.875f*a1m; u0 = 0.125f*a00 + 0.875f*a10; up = 0.125f*a0p + 0.875f*a1p; }
            else if (r == 2) { um = 0.875f*a1m + 0.125f*a2m; u0 = 0.875f*a10 + 0.125f*a20; up = 0.875f*a1p + 0.125f*a2p; }
            else             { um = 0.625f*a1m + 0.375f*a2m; u0 = 0.625f*a10 + 0.375f*a20; up = 0.625f*a1p + 0.375f*a2p; }

            float pmv[4];
            pmv[0] = 0.375f * um + 0.625f * u0;
            pmv[1] = 0.125f * um + 0.875f * u0;
            pmv[2] = 0.875f * u0 + 0.125f * up;
            pmv[3] = 0.625f * u0 + 0.375f * up;

            f32x4 ov;
            #pragma unroll
            for (int j = 0; j < 4; ++j) {
                bool pos = pmv[j] > 0.0f;
                ov[j] = pos ? 1.0f : 0.0f;
                if (pos) { ssum += 1.0f / (1.0f + __expf(-pmv[j])); scnt++; }
            }
            __builtin_nontemporal_store(ov, (f32x4*)(dst + r * 800));
        }
    }

    // deterministic block reduction (fixed order), one atomic pair per block
    for (int off = 32; off > 0; off >>= 1) {
        ssum += __shfl_down(ssum, off);
        scnt += __shfl_down(scnt, off);
    }
    __shared__ float wsum[4];
    __shared__ int wcnt[4];
    const int wid = threadIdx.x >> 6;
    const int lane = threadIdx.x & 63;
    if (lane == 0) { wsum[wid] = ssum; wcnt[wid] = scnt; }
    __syncthreads();
    if (threadIdx.x == 0) {
        float tt = wsum[0] + wsum[1] + wsum[2] + wsum[3];
        int c = wcnt[0] + wcnt[1] + wcnt[2] + wcnt[3];
        if (c > 0) {
            // fixed-point 2^32 accumulate -> bit-deterministic across replays
            atomicAdd(&acc_sig[bq], (ull)((double)tt * 4294967296.0 + 0.5));
            atomicAdd(&acc_cnt[bq], (unsigned int)c);
        }
        // order: our acc atomics complete (at coherence point) before done++.
        // atomics-only data => no buffer_wbl2 needed (round 4 lesson).
        asm volatile("s_waitcnt vmcnt(0)" ::: "memory");
        unsigned int old = atomicAdd(&done[bq], 1u);
        if (old == 156u) {                     // last of 157 blocks for this bq
            ull sig_fp = atomicAdd(&acc_sig[bq], 0ull);       // atomic read
            unsigned int cnt = atomicAdd(&acc_cnt[bq], 0u);   // atomic read
            float sig = (float)((double)sig_fp * (1.0 / 4294967296.0));
            float obj = sig / ((float)cnt + 1e-6f);
            float ps = ws_val[bq] * obj;
            out[(size_t)bq * 5 + 4] = ps;
            bool keep = (cnt > 5u) && (ws_area[bq] > 10.0f) && (ps > 0.05f);
            out[(size_t)(BB * KK * 6) + (size_t)BB * KK * 640000 + bq] = keep ? 1.0f : 0.0f;
        }
    }
}

// ---------------------------------------------------------------------------
// Kernel B-generic: fallback for pix != 640000 (unused for this problem).
// ---------------------------------------------------------------------------
__global__ __launch_bounds__(256) void mdh_masks_kernel(
    const float* __restrict__ mp,
    const int* __restrict__ ws_qidx,
    const int* __restrict__ hptr,
    const int* __restrict__ wptr,
    float* __restrict__ out_masks,
    ull* __restrict__ acc_sig,
    unsigned int* __restrict__ acc_cnt)
{
    const int bq = blockIdx.y;
    const int b = bq / KK;
    const int q = ws_qidx[bq];
    const int h = *hptr, w = *wptr;
    const long long pix = (long long)h * w;
    const float* __restrict__ src = mp + ((size_t)(b * QQ + q)) * (HM * WM);
    const float sy = (float)HM / (float)h;
    const float sx = (float)WM / (float)w;

    const long long p0 = (long long)blockIdx.x * 1024 + (long long)threadIdx.x * 4;
    float ssum = 0.0f;
    int scnt = 0;
    if (p0 < pix) {
        float pmv[4];
        for (int j = 0; j < 4; ++j) {
            long long p = p0 + j;
            if (p >= pix) { pmv[j] = -1.0f; continue; }
            int yy = (int)(p / w);
            int xx = (int)(p - (long long)yy * w);
            float yi = ((float)yy + 0.5f) * sy - 0.5f;
            float rf = floorf(yi); float fy = yi - rf;
            int r0 = max((int)rf, 0); int r1 = min((int)rf + 1, HM - 1);
            float xi = ((float)xx + 0.5f) * sx - 0.5f;
            float cf = floorf(xi); float fx = xi - cf;
            int c0 = max((int)cf, 0); int c1 = min((int)cf + 1, WM - 1);
            float a  = src[r0 * WM + c0], b2 = src[r0 * WM + c1];
            float c  = src[r1 * WM + c0], d2 = src[r1 * WM + c1];
            float t0 = (1.0f - fy) * a  + fy * c;
            float t1 = (1.0f - fy) * b2 + fy * d2;
            pmv[j] = (1.0f - fx) * t0 + fx * t1;
        }
        for (int j = 0; j < 4; ++j) {
            long long p = p0 + j;
            if (p >= pix) continue;
            bool pos = pmv[j] > 0.0f;
            out_masks[(size_t)bq * pix + p] = pos ? 1.0f : 0.0f;
            if (pos) { ssum += 1.0f / (1.0f + __expf(-pmv[j])); scnt++; }
        }
    }

    for (int off = 32; off > 0; off >>= 1) {
        ssum += __shfl_down(ssum, off);
        scnt += __shfl_down(scnt, off);
    }
    __shared__ float wsum[4];
    __shared__ int wcnt[4];
    const int wid = threadIdx.x >> 6;
    const int lane = threadIdx.x & 63;
    if (lane == 0) { wsum[wid] = ssum; wcnt[wid] = scnt; }
    __syncthreads();
    if (threadIdx.x == 0) {
        float tt = wsum[0] + wsum[1] + wsum[2] + wsum[3];
        int c = wcnt[0] + wcnt[1] + wcnt[2] + wcnt[3];
        if (c > 0) {
            atomicAdd(&acc_sig[bq], (ull)((double)tt * 4294967296.0 + 0.5));
            atomicAdd(&acc_cnt[bq], (unsigned int)c);
        }
    }
}

// ---------------------------------------------------------------------------
// Kernel C: final pass for the generic fallback path only.
// ---------------------------------------------------------------------------
__global__ void mdh_final_kernel(
    const ull* __restrict__ acc_sig,
    const unsigned int* __restrict__ acc_cnt,
    const float* __restrict__ ws_val,
    const float* __restrict__ ws_area,
    float* __restrict__ out,
    long long pix)
{
    int t = blockIdx.x * blockDim.x + threadIdx.x;
    if (t < BB * KK) {
        float sig = (float)((double)acc_sig[t] * (1.0 / 4294967296.0));
        unsigned int cnt = acc_cnt[t];
        float obj = sig / ((float)cnt + 1e-6f);
        float ps = ws_val[t] * obj;
        out[(size_t)t * 5 + 4] = ps;
        bool keep = (cnt > 5) && (ws_area[t] > 10.0f) && (ps > 0.05f);
        out[(size_t)(BB * KK * 5 + BB * KK) + (size_t)BB * KK * pix + t] = keep ? 1.0f : 0.0f;
    }
}

extern "C" void kernel_launch(void* const* d_in, const int* in_sizes, int n_in,
                              void* d_out, int out_size, void* d_ws, size_t ws_size,
                              hipStream_t stream)
{
    const float* mp    = (const float*)d_in[0];   // (B,Q,200,200) f32
    const float* cls   = (const float*)d_in[1];   // (B,Q,80) f32
    const float* boxes = (const float*)d_in[2];   // (B,Q,4) f32
    const int* hptr    = (const int*)d_in[3];     // scalar h
    const int* wptr    = (const int*)d_in[4];     // scalar w
    float* out = (float*)d_out;

    // out layout: boxes_scores (B*K*5) | labels (B*K) | masks (B*K*h*w) | keep (B*K)
    const long long pix = ((long long)out_size - (long long)BB * KK * 7) / ((long long)BB * KK);

    char* wsb = (char*)d_ws;
    ull* acc_sig          = (ull*)wsb;                       // 200*8    @0
    unsigned int* acc_cnt = (unsigned int*)(wsb + 1600);     // 200*4    @1600
    float* ws_val         = (float*)(wsb + 2400);            // 200*4    @2400
    int* ws_qidx          = (int*)(wsb + 3200);              // 200*4    @3200
    float* ws_area        = (float*)(wsb + 4000);            // 200*4    @4000
    unsigned int* ws_done = (unsigned int*)(wsb + 4800);     // 200*4    @4800
    unsigned int* ws_keys = (unsigned int*)(wsb + 5600);     // 48000*4  @5600 (16B aligned)

    mdh_topk_kernel<<<BB, 1024, 0, stream>>>(cls, ws_keys, boxes, hptr, wptr, out,
                                             ws_val, ws_qidx, ws_area,
                                             acc_sig, acc_cnt, ws_done);

    if (pix == 640000) {
        mdh_masks800_kernel<<<200 * 157, 256, 0, stream>>>(
            mp, ws_qidx, ws_val, ws_area, out, acc_sig, acc_cnt, ws_done);
    } else {
        const int nblk = (int)((pix + 1023) / 1024);
        mdh_masks_kernel<<<dim3(nblk, BB * KK), 256, 0, stream>>>(
            mp, ws_qidx, hptr, wptr, out + BB * KK * 6, acc_sig, acc_cnt);
        mdh_final_kernel<<<1, 256, 0, stream>>>(acc_sig, acc_cnt, ws_val, ws_area, out, pix);
    }
}